// Round 1
// baseline (71623.236 us; speedup 1.0000x reference)
//
#include <hip/hip_runtime.h>
#include <math.h>

// Problem dims (fixed)
#define BD    64      // batch
#define SEQ   64      // S_EN == S_FR
#define EMBD  512
#define UNITS 1024
#define NG    4096    // 4*UNITS
#define VFR   16000

__device__ __forceinline__ float sigm(float x) { return 1.0f / (1.0f + __expf(-x)); }

__global__ __launch_bounds__(256) void zero_f(float* __restrict__ p, int n) {
    int i = blockIdx.x * 256 + threadIdx.x;
    if (i < n) p[i] = 0.f;
}

// ---------------------------------------------------------------------------
// Tiled fp32 GEMM: C[M,N] = A[M,K] @ B[K,N] (+bias). 128x128 tile, 8x8 micro.
// PERMUTE: output row r=t*64+b is written to row b*64+t (hs layout -> logits).
// ---------------------------------------------------------------------------
template <bool PERMUTE>
__global__ __launch_bounds__(256) void sgemm128(
    const float* __restrict__ A, const float* __restrict__ Bm,
    const float* __restrict__ bias, float* __restrict__ C, int N, int K)
{
    __shared__ float As[8][128];
    __shared__ float Bs[8][128];
    const int tid = threadIdx.x;
    const int bx = blockIdx.x, by = blockIdx.y;
    const int tx = tid & 15, ty = tid >> 4;
    const int arow = by * 128 + (tid >> 1);
    const int ak   = (tid & 1) << 2;
    const int bk   = tid >> 5;
    const int bn   = (tid & 31) << 2;

    float acc[8][8];
#pragma unroll
    for (int i = 0; i < 8; ++i)
#pragma unroll
        for (int j = 0; j < 8; ++j) acc[i][j] = 0.f;

    for (int k0 = 0; k0 < K; k0 += 8) {
        float4 av = *(const float4*)(A + (size_t)arow * K + k0 + ak);
        float4 bv = *(const float4*)(Bm + (size_t)(k0 + bk) * N + bx * 128 + bn);
        __syncthreads();
        As[ak + 0][tid >> 1] = av.x;
        As[ak + 1][tid >> 1] = av.y;
        As[ak + 2][tid >> 1] = av.z;
        As[ak + 3][tid >> 1] = av.w;
        *(float4*)(&Bs[bk][bn]) = bv;
        __syncthreads();
#pragma unroll
        for (int kk = 0; kk < 8; ++kk) {
            float a[8], b[8];
#pragma unroll
            for (int i = 0; i < 8; ++i) a[i] = As[kk][ty * 8 + i];
#pragma unroll
            for (int j = 0; j < 8; ++j) b[j] = Bs[kk][tx * 8 + j];
#pragma unroll
            for (int i = 0; i < 8; ++i)
#pragma unroll
                for (int j = 0; j < 8; ++j) acc[i][j] += a[i] * b[j];
        }
    }
#pragma unroll
    for (int i = 0; i < 8; ++i) {
        int r    = by * 128 + ty * 8 + i;
        int orow = PERMUTE ? (((r & 63) << 6) | (r >> 6)) : r;
        float* crow = C + (size_t)orow * N + bx * 128 + tx * 8;
#pragma unroll
        for (int j = 0; j < 8; ++j) {
            float v = acc[i][j];
            if (bias) v += bias[bx * 128 + tx * 8 + j];
            crow[j] = v;
        }
    }
}

// Same GEMM but A rows gathered from an embedding table: A[r][k] = emb[idx[r]][k].
__global__ __launch_bounds__(256) void sgemm128_embed(
    const float* __restrict__ emb, const int* __restrict__ idxv,
    const float* __restrict__ Bm, const float* __restrict__ bias,
    float* __restrict__ C, int N, int K)
{
    __shared__ float As[8][128];
    __shared__ float Bs[8][128];
    const int tid = threadIdx.x;
    const int bx = blockIdx.x, by = blockIdx.y;
    const int tx = tid & 15, ty = tid >> 4;
    const int arow = by * 128 + (tid >> 1);
    const int ak   = (tid & 1) << 2;
    const int bk   = tid >> 5;
    const int bn   = (tid & 31) << 2;
    const int gidx = idxv[arow];

    float acc[8][8];
#pragma unroll
    for (int i = 0; i < 8; ++i)
#pragma unroll
        for (int j = 0; j < 8; ++j) acc[i][j] = 0.f;

    for (int k0 = 0; k0 < K; k0 += 8) {
        float4 av = *(const float4*)(emb + (size_t)gidx * K + k0 + ak);
        float4 bv = *(const float4*)(Bm + (size_t)(k0 + bk) * N + bx * 128 + bn);
        __syncthreads();
        As[ak + 0][tid >> 1] = av.x;
        As[ak + 1][tid >> 1] = av.y;
        As[ak + 2][tid >> 1] = av.z;
        As[ak + 3][tid >> 1] = av.w;
        *(float4*)(&Bs[bk][bn]) = bv;
        __syncthreads();
#pragma unroll
        for (int kk = 0; kk < 8; ++kk) {
            float a[8], b[8];
#pragma unroll
            for (int i = 0; i < 8; ++i) a[i] = As[kk][ty * 8 + i];
#pragma unroll
            for (int j = 0; j < 8; ++j) b[j] = Bs[kk][tx * 8 + j];
#pragma unroll
            for (int i = 0; i < 8; ++i)
#pragma unroll
                for (int j = 0; j < 8; ++j) acc[i][j] += a[i] * b[j];
        }
    }
#pragma unroll
    for (int i = 0; i < 8; ++i) {
        int r = by * 128 + ty * 8 + i;
        float* crow = C + (size_t)r * N + bx * 128 + tx * 8;
#pragma unroll
        for (int j = 0; j < 8; ++j) crow[j] = acc[i][j] + bias[bx * 128 + tx * 8 + j];
    }
}

// ---------------------------------------------------------------------------
// One LSTM time step, fused: z = xW[row(b,t)] (+ A1@B1) + h_prev@U ; gates ;
// writes h_out (= h history slice) and c_out (ping-pong).
// Grid = 256 blocks: bt = blk>>6 (batch tile of 16), ut = blk&63 (16 u cols).
// Each block computes the 16x64 z-tile covering all 4 gates for its u cols.
// ---------------------------------------------------------------------------
__global__ __launch_bounds__(256) void lstm_step(
    const float* __restrict__ xW, int t,
    const float* __restrict__ A1, const float* __restrict__ B1,   // optional (decoder ctx term)
    const float* __restrict__ h_prev, const float* __restrict__ U,
    const float* __restrict__ c_prev,
    float* __restrict__ h_out, float* __restrict__ c_out)
{
    __shared__ float hsm[64][16];   // [k within chunk][row] (transposed for b128 broadcast)
    __shared__ float zsm[16][64];
    const int tid = threadIdx.x;
    const int bt = blockIdx.x >> 6, ut = blockIdx.x & 63;
    const int cc = tid & 63;        // z-col within tile
    const int rg = tid >> 6;        // row group (wave id): rows rg*4..rg*4+3
    const int gate = cc >> 4, uu = cc & 15;
    const int n = ut * 16 + uu + gate * 1024;

    float acc[4];
#pragma unroll
    for (int j = 0; j < 4; ++j) {
        int b = bt * 16 + rg * 4 + j;
        acc[j] = xW[(size_t)(b * SEQ + t) * NG + n];
    }

#pragma unroll 1
    for (int term = 0; term < 2; ++term) {
        const float* Ax = (term == 0) ? A1 : h_prev;
        const float* Bx = (term == 0) ? B1 : U;
        if (Ax == nullptr) continue;
        for (int k0 = 0; k0 < 1024; k0 += 64) {
            __syncthreads();
            {
                int r = tid >> 4, k4 = (tid & 15) << 2;
                float4 v = *(const float4*)(Ax + (size_t)(bt * 16 + r) * 1024 + k0 + k4);
                hsm[k4 + 0][r] = v.x;
                hsm[k4 + 1][r] = v.y;
                hsm[k4 + 2][r] = v.z;
                hsm[k4 + 3][r] = v.w;
            }
            __syncthreads();
#pragma unroll 8
            for (int kk = 0; kk < 64; ++kk) {
                float uv = Bx[(size_t)(k0 + kk) * NG + n];
                float4 hv = *(const float4*)(&hsm[kk][rg * 4]);   // wave-uniform -> broadcast
                acc[0] += hv.x * uv;
                acc[1] += hv.y * uv;
                acc[2] += hv.z * uv;
                acc[3] += hv.w * uv;
            }
        }
    }

    __syncthreads();
#pragma unroll
    for (int j = 0; j < 4; ++j) zsm[rg * 4 + j][cc] = acc[j];
    __syncthreads();
    {
        const int r = tid >> 4, u2 = tid & 15;
        const int b = bt * 16 + r, u = ut * 16 + u2;
        float zi = zsm[r][u2];
        float zf = zsm[r][16 + u2];
        float zg = zsm[r][32 + u2];
        float zo = zsm[r][48 + u2];
        float cp = c_prev[b * 1024 + u];
        float cn = sigm(zf) * cp + sigm(zi) * tanhf(zg);
        float hn = sigm(zo) * tanhf(cn);
        c_out[b * 1024 + u] = cn;
        h_out[b * 1024 + u] = hn;
    }
}

// ---------------------------------------------------------------------------
// q = h @ Wq   (M=64, N=1024, K=1024). 64 blocks; block handles 16 cols.
// ---------------------------------------------------------------------------
__global__ __launch_bounds__(256) void q_proj(
    const float* __restrict__ h, const float* __restrict__ Wq, float* __restrict__ q)
{
    __shared__ float hq[64][16];    // [k][row]
    const int tid = threadIdx.x;
    const int ut = blockIdx.x;
    const int col = tid & 15;       // 0..15
    const int rg = tid >> 4;        // 0..15 -> rows rg*4..+3
    const int n = ut * 16 + col;
    float acc[4] = {0.f, 0.f, 0.f, 0.f};
    for (int k0 = 0; k0 < 1024; k0 += 64) {
        __syncthreads();
#pragma unroll
        for (int i = 0; i < 4; ++i) {
            int idx = tid + i * 256;            // 0..1023 float4s
            int r = idx >> 4, k4 = (idx & 15) << 2;
            float4 v = *(const float4*)(h + (size_t)r * 1024 + k0 + k4);
            hq[k4 + 0][r] = v.x;
            hq[k4 + 1][r] = v.y;
            hq[k4 + 2][r] = v.z;
            hq[k4 + 3][r] = v.w;
        }
        __syncthreads();
#pragma unroll 8
        for (int kk = 0; kk < 64; ++kk) {
            float wqv = Wq[(size_t)(k0 + kk) * 1024 + n];
            float4 hv = *(const float4*)(&hq[kk][rg * 4]);
            acc[0] += hv.x * wqv;
            acc[1] += hv.y * wqv;
            acc[2] += hv.z * wqv;
            acc[3] += hv.w * wqv;
        }
    }
#pragma unroll
    for (int j = 0; j < 4; ++j) q[(size_t)(rg * 4 + j) * 1024 + n] = acc[j];
}

// ---------------------------------------------------------------------------
// Additive attention for one step: scores -> mask -> softmax -> context.
// One block per batch element.
// ---------------------------------------------------------------------------
__global__ __launch_bounds__(256) void attn_ctx(
    const float* __restrict__ q, const float* __restrict__ kproj,
    const float* __restrict__ en_o, const int* __restrict__ valid_len,
    const float* __restrict__ wv, float* __restrict__ ctx)
{
    const int b = blockIdx.x;
    const int tid = threadIdx.x;
    const int lane = tid & 63, wave = tid >> 6;
    __shared__ float qs[1024];
    __shared__ float sc[64];
    __shared__ float at[64];

    for (int i = tid; i < 1024; i += 256) qs[i] = q[b * 1024 + i];
    __syncthreads();

    for (int s = wave; s < 64; s += 4) {
        const float* kp = kproj + ((size_t)s * BD + b) * 1024;
        float p = 0.f;
        for (int u = lane; u < 1024; u += 64)
            p += wv[u] * tanhf(qs[u] + kp[u]);
#pragma unroll
        for (int off = 32; off; off >>= 1) p += __shfl_down(p, off, 64);
        if (lane == 0) sc[s] = p;
    }
    __syncthreads();

    if (tid < 64) {
        int vl = valid_len[b];
        float v = (tid < vl) ? sc[tid] : -1000000.0f;
        float m = v;
#pragma unroll
        for (int off = 32; off; off >>= 1) m = fmaxf(m, __shfl_xor(m, off, 64));
        float e = __expf(v - m);
        float ssum = e;
#pragma unroll
        for (int off = 32; off; off >>= 1) ssum += __shfl_xor(ssum, off, 64);
        at[tid] = e / ssum;
    }
    __syncthreads();

    const int u0 = tid * 4;
    float a0 = 0.f, a1 = 0.f, a2 = 0.f, a3 = 0.f;
    for (int s = 0; s < 64; ++s) {
        float a = at[s];
        float4 eo = *(const float4*)(en_o + ((size_t)s * BD + b) * 1024 + u0);
        a0 += a * eo.x; a1 += a * eo.y; a2 += a * eo.z; a3 += a * eo.w;
    }
    float4 o = {a0, a1, a2, a3};
    *(float4*)(ctx + (size_t)b * 1024 + u0) = o;
}

// ---------------------------------------------------------------------------
extern "C" void kernel_launch(void* const* d_in, const int* in_sizes, int n_in,
                              void* d_out, int out_size, void* d_ws, size_t ws_size,
                              hipStream_t stream)
{
    const int*   en        = (const int*)d_in[0];
    const int*   fr        = (const int*)d_in[1];
    const int*   valid_len = (const int*)d_in[2];
    const float* en_emb    = (const float*)d_in[3];
    const float* de_emb    = (const float*)d_in[4];
    const float* en_W      = (const float*)d_in[5];
    const float* en_U      = (const float*)d_in[6];
    const float* en_b      = (const float*)d_in[7];
    const float* de_W      = (const float*)d_in[8];
    const float* de_U      = (const float*)d_in[9];
    const float* de_b      = (const float*)d_in[10];
    const float* Wq        = (const float*)d_in[11];
    const float* Wk        = (const float*)d_in[12];
    const float* wv        = (const float*)d_in[13];
    const float* Wd        = (const float*)d_in[14];
    const float* bd        = (const float*)d_in[15];
    float* out = (float*)d_out;
    float* ws  = (float*)d_ws;

    // workspace layout (floats)
    float* xW_en = ws;                       // 4096 x 4096
    float* xW_fr = xW_en + 16777216;         // 4096 x 4096
    float* en_o  = xW_fr + 16777216;         // [t][b][u] 64*64*1024
    float* kproj = en_o + 4194304;           // [s][b][u]
    float* hs    = kproj + 4194304;          // [t][b][u]
    float* h0    = hs + 4194304;             // 64*1024 zeros
    float* cb0   = h0 + 65536;               // c ping-pong
    float* cb1   = cb0 + 65536;
    float* qbuf  = cb1 + 65536;              // 64*1024
    float* ctx   = qbuf + 65536;             // 64*1024

    // zero h0 + cb0 (contiguous)
    zero_f<<<dim3(512), dim3(256), 0, stream>>>(h0, 131072);

    // x @ W precompute (embedding gather fused), bias folded in
    sgemm128_embed<<<dim3(32, 32), dim3(256), 0, stream>>>(
        en_emb, en, en_W, en_b, xW_en, NG, EMBD);
    sgemm128_embed<<<dim3(32, 32), dim3(256), 0, stream>>>(
        de_emb, fr, de_W + (size_t)UNITS * NG, de_b, xW_fr, NG, EMBD);

    // encoder
    for (int t = 0; t < SEQ; ++t) {
        const float* hp = (t == 0) ? h0 : en_o + (size_t)(t - 1) * 65536;
        const float* cp = (t & 1) ? cb1 : cb0;
        float*       cn = (t & 1) ? cb0 : cb1;
        lstm_step<<<dim3(256), dim3(256), 0, stream>>>(
            xW_en, t, nullptr, nullptr, hp, en_U, cp, en_o + (size_t)t * 65536, cn);
    }

    // kproj = en_o @ Wk
    sgemm128<false><<<dim3(8, 32), dim3(256), 0, stream>>>(
        en_o, Wk, nullptr, kproj, 1024, 1024);

    // decoder
    for (int t = 0; t < SEQ; ++t) {
        const float* hp = (t == 0) ? en_o + (size_t)63 * 65536 : hs + (size_t)(t - 1) * 65536;
        const float* cp = (t & 1) ? cb1 : cb0;   // parity continues from encoder (64 even)
        float*       cn = (t & 1) ? cb0 : cb1;
        q_proj<<<dim3(64), dim3(256), 0, stream>>>(hp, Wq, qbuf);
        attn_ctx<<<dim3(64), dim3(256), 0, stream>>>(qbuf, kproj, en_o, valid_len, wv, ctx);
        lstm_step<<<dim3(256), dim3(256), 0, stream>>>(
            xW_fr, t, ctx, de_W, hp, de_U, cp, hs + (size_t)t * 65536, cn);
    }

    // logits = hs @ Wd + bd, with [t][b] -> [b][t] row permutation
    sgemm128<true><<<dim3(125, 32), dim3(256), 0, stream>>>(
        hs, Wd, bd, out, VFR, 1024);
}

// Round 2
// 41846.497 us; speedup vs baseline: 1.7116x; 1.7116x over previous
//
#include <hip/hip_runtime.h>
#include <math.h>

// dims
#define BD    64
#define SEQ   64
#define EMBD  512
#define UNITS 1024
#define NG    4096
#define VFR   16000

typedef __attribute__((ext_vector_type(8))) short bf16x8;
typedef __attribute__((ext_vector_type(4))) float f32x4;

__device__ __forceinline__ float sigm(float x) { return 1.0f / (1.0f + __expf(-x)); }
__device__ __forceinline__ float tanh_f(float x) {
    float e = __expf(2.0f * x);
    return 1.0f - 2.0f / (e + 1.0f);
}
__device__ __forceinline__ unsigned bf16bits(float v) {
    unsigned u = __float_as_uint(v);
    return (u + 0x7FFFu + ((u >> 16) & 1u)) >> 16;
}
__device__ __forceinline__ float bf2f(short s) {
    return __uint_as_float(((unsigned)(unsigned short)s) << 16);
}
__device__ __forceinline__ void split2(float v, short& h, short& l) {
    unsigned hb = bf16bits(v);
    float hv = __uint_as_float(hb << 16);
    h = (short)hb;
    l = (short)bf16bits(v - hv);
}

// ---------------- grid barrier (all blocks co-resident: 256 blocks, 1/CU) ---
__device__ __forceinline__ void gbar(int* cnt, int* gen, int nb) {
    __threadfence();
    __syncthreads();
    if (threadIdx.x == 0) {
        int g = __hip_atomic_load(gen, __ATOMIC_RELAXED, __HIP_MEMORY_SCOPE_AGENT);
        if (atomicAdd(cnt, 1) == nb - 1) {
            __hip_atomic_store(cnt, 0, __ATOMIC_RELAXED, __HIP_MEMORY_SCOPE_AGENT);
            __hip_atomic_store(gen, g + 1, __ATOMIC_RELEASE, __HIP_MEMORY_SCOPE_AGENT);
        } else {
            while (__hip_atomic_load(gen, __ATOMIC_RELAXED, __HIP_MEMORY_SCOPE_AGENT) == g)
                __builtin_amdgcn_s_sleep(8);
        }
    }
    __syncthreads();
    __threadfence();
}

__global__ __launch_bounds__(64) void zero16(int* p) {
    if (threadIdx.x < 16) p[threadIdx.x] = 0;
}

// ---------------- prep: embedding gather -> bf16 [4096][512] ----------------
__global__ __launch_bounds__(256) void gather_bf16(
    const float* __restrict__ emb, const int* __restrict__ idx,
    short* __restrict__ dst, int K)
{
    int row = blockIdx.x;
    int g = idx[row];
    const float* src = emb + (size_t)g * K;
    for (int k = threadIdx.x * 2; k < K; k += 512) {
        float2 v = *(const float2*)&src[k];
        dst[(size_t)row * K + k]     = (short)bf16bits(v.x);
        dst[(size_t)row * K + k + 1] = (short)bf16bits(v.y);
    }
}

// ---------------- prep: transpose (+optional split) src[K][N] -> d[N][K] ----
template <bool SPLIT>
__global__ __launch_bounds__(256) void transp_split(
    const float* __restrict__ src, int N, int K,
    short* __restrict__ dh, short* __restrict__ dl)
{
    __shared__ float sm[32][33];
    const int tid = threadIdx.x;
    const int nt = blockIdx.x * 32, kt = blockIdx.y * 32;
    {
        int r = tid >> 3, c4 = (tid & 7) * 4;
        float4 v = *(const float4*)&src[(size_t)(kt + r) * N + nt + c4];
        sm[r][c4] = v.x; sm[r][c4 + 1] = v.y; sm[r][c4 + 2] = v.z; sm[r][c4 + 3] = v.w;
    }
    __syncthreads();
    {
        int n = tid >> 3, k4 = (tid & 7) * 4;
        short4 hh, ll;
        short a, b;
        split2(sm[k4 + 0][n], a, b); hh.x = a; ll.x = b;
        split2(sm[k4 + 1][n], a, b); hh.y = a; ll.y = b;
        split2(sm[k4 + 2][n], a, b); hh.z = a; ll.z = b;
        split2(sm[k4 + 3][n], a, b); hh.w = a; ll.w = b;
        *(short4*)&dh[(size_t)(nt + n) * K + kt + k4] = hh;
        if (SPLIT) *(short4*)&dl[(size_t)(nt + n) * K + kt + k4] = ll;
    }
}

// ---------------- split-bf16 MFMA GEMM: C[M,N] = A[M,K] * B[N,K]^T ----------
// 128x128 tile, 4 waves each 64x64 (4x4 of 16x16x32 mfma).
// LDS in fragment order: subtile slot = 64 lanes * 16B, ds_read_b128 conflict-free.
// OMODE: 0 = f32, 1 = f32 + row-permute (t*64+b -> b*64+t), 2 = bf16 out.
template <int OMODE, bool SA, bool SB>
__global__ __launch_bounds__(256, 2) void gemm_split(
    const short* __restrict__ Ah, const short* __restrict__ Al,
    const short* __restrict__ Bh, const short* __restrict__ Bl,
    const float* __restrict__ bias, void* __restrict__ Cout, int N, int K)
{
    __shared__ short lds[32 * 512];   // 32 subtiles * 64 lanes * 8 shorts = 32KB
    const int tid = threadIdx.x;
    const int lane = tid & 63, w = tid >> 6;
    const int bm = blockIdx.y, bn = blockIdx.x;
    const int wm = w & 1, wn = w >> 1;
    const int r15 = lane & 15, q = lane >> 4;

    f32x4 zero4 = {0.f, 0.f, 0.f, 0.f};
    f32x4 acc[4][4];
#pragma unroll
    for (int i = 0; i < 4; ++i)
#pragma unroll
        for (int j = 0; j < 4; ++j) acc[i][j] = zero4;

    const short* gsrc[8];
    bool use[8];
#pragma unroll
    for (int i = 0; i < 8; ++i) {
        int st = w * 8 + i;
        int mat = st >> 4, hl = (st >> 3) & 1, mt = st & 7;
        const short* base = (mat == 0) ? (hl ? Al : Ah) : (hl ? Bl : Bh);
        use[i] = (mat == 0) ? (SA || hl == 0) : (SB || hl == 0);
        int row = ((mat == 0) ? bm : bn) * 128 + mt * 16 + r15;
        gsrc[i] = base + (size_t)row * K + q * 8;
    }

    for (int k0 = 0; k0 < K; k0 += 32) {
        int4 stg[8];
#pragma unroll
        for (int i = 0; i < 8; ++i)
            if (use[i]) stg[i] = *(const int4*)(gsrc[i] + k0);
        __syncthreads();
#pragma unroll
        for (int i = 0; i < 8; ++i)
            if (use[i]) *(int4*)&lds[(size_t)((w * 8 + i) * 64 + lane) * 8] = stg[i];
        __syncthreads();

        bf16x8 ah[4], al[4], bh[4], bl[4];
#pragma unroll
        for (int i = 0; i < 4; ++i) {
            ah[i] = *(const bf16x8*)&lds[(((wm * 4 + i) * 64) + lane) * 8];
            if (SA) al[i] = *(const bf16x8*)&lds[(((8 + wm * 4 + i) * 64) + lane) * 8];
            bh[i] = *(const bf16x8*)&lds[(((16 + wn * 4 + i) * 64) + lane) * 8];
            if (SB) bl[i] = *(const bf16x8*)&lds[(((24 + wn * 4 + i) * 64) + lane) * 8];
        }
#pragma unroll
        for (int i = 0; i < 4; ++i)
#pragma unroll
            for (int j = 0; j < 4; ++j) {
                acc[i][j] = __builtin_amdgcn_mfma_f32_16x16x32_bf16(ah[i], bh[j], acc[i][j], 0, 0, 0);
                if (SA) acc[i][j] = __builtin_amdgcn_mfma_f32_16x16x32_bf16(al[i], bh[j], acc[i][j], 0, 0, 0);
                if (SB) acc[i][j] = __builtin_amdgcn_mfma_f32_16x16x32_bf16(ah[i], bl[j], acc[i][j], 0, 0, 0);
            }
    }

#pragma unroll
    for (int i = 0; i < 4; ++i) {
        int rowbase = bm * 128 + wm * 64 + i * 16 + q * 4;
#pragma unroll
        for (int j = 0; j < 4; ++j) {
            int col = bn * 128 + wn * 64 + j * 16 + r15;
            float bv = bias ? bias[col] : 0.f;
#pragma unroll
            for (int rI = 0; rI < 4; ++rI) {
                int row = rowbase + rI;
                float v = acc[i][j][rI] + bv;
                if (OMODE == 1) {
                    int orow = ((row & 63) << 6) | (row >> 6);
                    ((float*)Cout)[(size_t)orow * N + col] = v;
                } else if (OMODE == 0) {
                    ((float*)Cout)[(size_t)row * N + col] = v;
                } else {
                    ((short*)Cout)[(size_t)row * N + col] = (short)bf16bits(v);
                }
            }
        }
    }
}

// ---------------- shared pieces of the persistent recurrent kernels --------
// z-accumulation of h @ U for 16 columns (n = blk*16 + c16), 2 batch rows/thread.
__device__ __forceinline__ void accum_hU(
    float& a0, float& a1, const float* __restrict__ h_ws,
    const float* __restrict__ U, int n, int b0, int tid,
    float (*hsm)[66])
{
    for (int k0 = 0; k0 < 1024; k0 += 64) {
        __syncthreads();
#pragma unroll
        for (int i = 0; i < 2; ++i) {
            int idx4 = tid * 2 + i;                 // 0..1023
            int bb = idx4 >> 4, kq = (idx4 & 15) * 4;
            float4 v = *(const float4*)&h_ws[bb * 1024 + k0 + kq];
            hsm[kq + 0][bb] = v.x;
            hsm[kq + 1][bb] = v.y;
            hsm[kq + 2][bb] = v.z;
            hsm[kq + 3][bb] = v.w;
        }
        __syncthreads();
#pragma unroll 8
        for (int kk = 0; kk < 64; ++kk) {
            float uv = U[(size_t)(k0 + kk) * NG + n];
            float2 hv = *(const float2*)&hsm[kk][b0];
            a0 += hv.x * uv;
            a1 += hv.y * uv;
        }
    }
}

__device__ __forceinline__ void lstm_gate_phase(
    int t, int blk, int tid, const float* __restrict__ z_ws,
    float* __restrict__ h_ws, float* __restrict__ c_ws,
    short* __restrict__ oh, short* __restrict__ ol)
{
    int g2 = blk * 512 + tid;
    if (g2 < 65536) {
        int b = g2 >> 10, u = g2 & 1023;
        const float* zr = z_ws + b * NG;
        float zi = zr[u], zf = zr[u + 1024], zg = zr[u + 2048], zo = zr[u + 3072];
        float cp = c_ws[g2];
        float cn = sigm(zf) * cp + sigm(zi) * tanh_f(zg);
        float hn = sigm(zo) * tanh_f(cn);
        c_ws[g2] = cn;
        h_ws[g2] = hn;
        short hh, hl;
        split2(hn, hh, hl);
        size_t o = (size_t)(t * 64 + b) * 1024 + u;
        oh[o] = hh;
        ol[o] = hl;
    }
}

// ---------------- encoder: 64 steps, persistent, 256 blocks x 512 ----------
__global__ __launch_bounds__(512, 2) void encoder_persist(
    const short* __restrict__ xW,      // bf16 [4096 (b*64+t)][4096]
    const float* __restrict__ U,
    float* __restrict__ h_ws, float* __restrict__ c_ws, float* __restrict__ z_ws,
    short* __restrict__ eo_h, short* __restrict__ eo_l,
    int* cnt, int* gen)
{
    __shared__ float hsm[64][66];
    const int tid = threadIdx.x;
    const int blk = blockIdx.x;
    {   // zero h, c
        int g = blk * 512 + tid;
        if (g < 65536) h_ws[g] = 0.f;
        else c_ws[g - 65536] = 0.f;
    }
    gbar(cnt, gen, 256);
    const int c16 = tid & 15, bg = tid >> 4;
    const int n = blk * 16 + c16;
    const int b0 = bg * 2;
    for (int t = 0; t < SEQ; ++t) {
        float a0 = bf2f(xW[(size_t)(b0 * 64 + t) * NG + n]);
        float a1 = bf2f(xW[(size_t)((b0 + 1) * 64 + t) * NG + n]);
        accum_hU(a0, a1, h_ws, U, n, b0, tid, hsm);
        z_ws[b0 * NG + n] = a0;
        z_ws[(b0 + 1) * NG + n] = a1;
        gbar(cnt, gen, 256);
        lstm_gate_phase(t, blk, tid, z_ws, h_ws, c_ws, eo_h, eo_l);
        gbar(cnt, gen, 256);
    }
}

// ---------------- decoder: 64 steps, persistent, 256 blocks x 512 ----------
__global__ __launch_bounds__(512, 2) void decoder_persist(
    const short* __restrict__ xW,      // bf16 [4096 (b*64+t)][4096]
    const float* __restrict__ U,
    const float* __restrict__ Wq, const float* __restrict__ wv,
    const float* __restrict__ kproj,   // f32 [4096 (s*64+b)][1024]
    const float* __restrict__ EOWc,    // f32 [4096 (s*64+b)][4096]
    const int* __restrict__ valid_len,
    float* __restrict__ h_ws, float* __restrict__ c_ws, float* __restrict__ z_ws,
    float* __restrict__ q_ws, float* __restrict__ sc_ws,
    short* __restrict__ hs_h, short* __restrict__ hs_l,
    int* cnt, int* gen)
{
    __shared__ float hsm[64][66];
    __shared__ float attn_sm[64][65];
    __shared__ float redq[64][8][4];
    const int tid = threadIdx.x;
    const int blk = blockIdx.x;

    for (int t = 0; t < SEQ; ++t) {
        // ---- phase A: q = h @ Wq (block owns 4 q-columns) ----
        {
            const int b = tid & 63;
            const int p8 = tid >> 6;              // 0..7 K-chunks of 128
            const int kbase = p8 * 128;
            const int u0 = blk * 4;
            float ax = 0.f, ay = 0.f, az = 0.f, aw = 0.f;
            const float* hrow = h_ws + b * 1024 + kbase;
            const float* wbase = Wq + (size_t)kbase * 1024 + u0;
#pragma unroll 8
            for (int k = 0; k < 128; k += 4) {
                float4 hv = *(const float4*)&hrow[k];
                float4 w0 = *(const float4*)&wbase[(size_t)(k + 0) * 1024];
                float4 w1 = *(const float4*)&wbase[(size_t)(k + 1) * 1024];
                float4 w2 = *(const float4*)&wbase[(size_t)(k + 2) * 1024];
                float4 w3 = *(const float4*)&wbase[(size_t)(k + 3) * 1024];
                ax += hv.x * w0.x + hv.y * w1.x + hv.z * w2.x + hv.w * w3.x;
                ay += hv.x * w0.y + hv.y * w1.y + hv.z * w2.y + hv.w * w3.y;
                az += hv.x * w0.z + hv.y * w1.z + hv.z * w2.z + hv.w * w3.z;
                aw += hv.x * w0.w + hv.y * w1.w + hv.z * w2.w + hv.w * w3.w;
            }
            redq[b][p8][0] = ax; redq[b][p8][1] = ay;
            redq[b][p8][2] = az; redq[b][p8][3] = aw;
            __syncthreads();
            if (tid < 64) {
                float sx = 0.f, sy = 0.f, sz = 0.f, sw = 0.f;
#pragma unroll
                for (int p = 0; p < 8; ++p) {
                    sx += redq[tid][p][0]; sy += redq[tid][p][1];
                    sz += redq[tid][p][2]; sw += redq[tid][p][3];
                }
                float4 o = {sx, sy, sz, sw};
                *(float4*)&q_ws[tid * 1024 + u0] = o;
            }
        }
        gbar(cnt, gen, 256);
        // ---- phase B: scores(b,s) = sum_u wv[u]*tanh(q[b,u]+kproj[s,b,u]) ----
        {
            const int p = tid >> 5, l32 = tid & 31;
            const int pair = blk * 16 + p;        // = s*64 + b
            const int b = pair & 63, s = pair >> 6;
            const float* kp = kproj + (size_t)pair * 1024;
            const float* qp = q_ws + b * 1024;
            float a = 0.f;
#pragma unroll
            for (int j = 0; j < 8; ++j) {
                int k = j * 128 + l32 * 4;
                float4 kv = *(const float4*)&kp[k];
                float4 qv = *(const float4*)&qp[k];
                float4 w4 = *(const float4*)&wv[k];
                a += w4.x * tanh_f(qv.x + kv.x);
                a += w4.y * tanh_f(qv.y + kv.y);
                a += w4.z * tanh_f(qv.z + kv.z);
                a += w4.w * tanh_f(qv.w + kv.w);
            }
#pragma unroll
            for (int off = 16; off; off >>= 1) a += __shfl_xor(a, off, 64);
            if (l32 == 0) sc_ws[b * 64 + s] = a;
        }
        gbar(cnt, gen, 256);
        // ---- phase C: z = xW + sum_s attn*EOWc + h @ U ----
        {
            if (tid < 64) {                       // per-b softmax (redundant per block)
                const int b = tid;
                const int vl = valid_len[b];
                float mx = -1e30f;
                for (int s = 0; s < 64; ++s) {
                    float v = (s < vl) ? sc_ws[b * 64 + s] : -1000000.0f;
                    attn_sm[b][s] = v;
                    mx = fmaxf(mx, v);
                }
                float sum = 0.f;
                for (int s = 0; s < 64; ++s) {
                    float e = __expf(attn_sm[b][s] - mx);
                    attn_sm[b][s] = e;
                    sum += e;
                }
                float r = 1.f / sum;
                for (int s = 0; s < 64; ++s) attn_sm[b][s] *= r;
            }
            __syncthreads();
            const int c16 = tid & 15, bg = tid >> 4;
            const int n = blk * 16 + c16;
            const int b0 = bg * 2;
            float a0 = bf2f(xW[(size_t)(b0 * 64 + t) * NG + n]);
            float a1 = bf2f(xW[(size_t)((b0 + 1) * 64 + t) * NG + n]);
#pragma unroll 4
            for (int s = 0; s < 64; ++s) {
                float w0 = attn_sm[b0][s], w1 = attn_sm[b0 + 1][s];
                a0 += w0 * EOWc[(size_t)(s * 64 + b0) * NG + n];
                a1 += w1 * EOWc[(size_t)(s * 64 + b0 + 1) * NG + n];
            }
            accum_hU(a0, a1, h_ws, U, n, b0, tid, hsm);
            z_ws[b0 * NG + n] = a0;
            z_ws[(b0 + 1) * NG + n] = a1;
        }
        gbar(cnt, gen, 256);
        // ---- phase G: gates ----
        lstm_gate_phase(t, blk, tid, z_ws, h_ws, c_ws, hs_h, hs_l);
        gbar(cnt, gen, 256);
    }
}

// ---------------------------------------------------------------------------
extern "C" void kernel_launch(void* const* d_in, const int* in_sizes, int n_in,
                              void* d_out, int out_size, void* d_ws, size_t ws_size,
                              hipStream_t stream)
{
    const int*   en        = (const int*)d_in[0];
    const int*   fr        = (const int*)d_in[1];
    const int*   valid_len = (const int*)d_in[2];
    const float* en_emb    = (const float*)d_in[3];
    const float* de_emb    = (const float*)d_in[4];
    const float* en_W      = (const float*)d_in[5];
    const float* en_U      = (const float*)d_in[6];
    const float* en_b      = (const float*)d_in[7];
    const float* de_W      = (const float*)d_in[8];
    const float* de_U      = (const float*)d_in[9];
    const float* de_b      = (const float*)d_in[10];
    const float* Wq        = (const float*)d_in[11];
    const float* Wk        = (const float*)d_in[12];
    const float* wv        = (const float*)d_in[13];
    const float* Wd        = (const float*)d_in[14];
    const float* bd        = (const float*)d_in[15];
    float* out = (float*)d_out;
    char*  ws  = (char*)d_ws;

    // ---- workspace regions (byte offsets; lifetimes annotated) ----
    float* EOWC  = (float*)(ws + 0);            // [4096][4096] f32 (EOWc gemm .. decoder)
    short* WDT_H = (short*)(ws + 0);            // [16000][1024] (after decoder)
    short* WDT_L = (short*)(ws + 33554432);
    short* XWEN  = (short*)(ws + 67108864);     // bf16 [4096][4096] (.. encoder)
    float* KPROJ = (float*)(ws + 67108864);     // f32 [4096][1024] (after encoder)
    short* XWFR  = (short*)(ws + 100663296);    // bf16 [4096][4096] (.. decoder)
    short* XEN   = (short*)(ws + 134217728);    // bf16 [4096][512]
    short* XFR   = (short*)(ws + 138412032);
    short* WCT_H = (short*)(ws + 134217728);    // bf16 [4096][1024] (after xW gemms)
    short* WCT_L = (short*)(ws + 142606336);
    short* HS_H  = (short*)(ws + 134217728);    // bf16 [4096][1024] (decoder ..)
    short* HS_L  = (short*)(ws + 142606336);
    short* ENWT  = (short*)(ws + 150994944);    // bf16 [4096][512]
    short* WXT   = (short*)(ws + 155189248);
    short* EO_H  = (short*)(ws + 150994944);    // bf16 [4096][1024] (encoder ..)
    short* EO_L  = (short*)(ws + 159383552);
    short* WKT_H = (short*)(ws + 167772160);    // bf16 [1024][1024]
    short* WKT_L = (short*)(ws + 169869312);
    float* ZWS   = (float*)(ws + 171966464);    // [64][4096]
    float* HWS   = (float*)(ws + 173015040);    // [64][1024]
    float* CWS   = (float*)(ws + 173277184);
    float* QWS   = (float*)(ws + 173539328);
    float* SCWS  = (float*)(ws + 173801472);    // [64][64]
    int*   BAR   = (int*)(ws + 173817856);      // cnt, gen

    zero16<<<1, 64, 0, stream>>>(BAR);

    // embedding gathers (single bf16: xW values are tiny, error negligible)
    gather_bf16<<<4096, 256, 0, stream>>>(en_emb, en, XEN, EMBD);
    gather_bf16<<<4096, 256, 0, stream>>>(de_emb, fr, XFR, EMBD);
    // weight transposes
    transp_split<false><<<dim3(128, 16), 256, 0, stream>>>(en_W, NG, EMBD, ENWT, nullptr);
    transp_split<false><<<dim3(128, 16), 256, 0, stream>>>(de_W + (size_t)UNITS * NG, NG, EMBD, WXT, nullptr);

    // xW = X @ W + b   (bf16 out)
    gemm_split<2, false, false><<<dim3(32, 32), 256, 0, stream>>>(
        XEN, XEN, ENWT, ENWT, en_b, XWEN, NG, EMBD);
    gemm_split<2, false, false><<<dim3(32, 32), 256, 0, stream>>>(
        XFR, XFR, WXT, WXT, de_b, XWFR, NG, EMBD);

    // Wc^T split (into X region, X dead)
    transp_split<true><<<dim3(128, 32), 256, 0, stream>>>(de_W, NG, UNITS, WCT_H, WCT_L);

    // encoder (writes eo splits into ENWT region, dead)
    encoder_persist<<<256, 512, 0, stream>>>(XWEN, en_U, HWS, CWS, ZWS, EO_H, EO_L, BAR, BAR + 8);

    // EOWc = en_o @ Wc  (f32)
    gemm_split<0, true, true><<<dim3(32, 32), 256, 0, stream>>>(
        EO_H, EO_L, WCT_H, WCT_L, nullptr, EOWC, NG, UNITS);

    // Wk^T split, then kproj = en_o @ Wk (into xW_en region, dead after encoder)
    transp_split<true><<<dim3(32, 32), 256, 0, stream>>>(Wk, UNITS, UNITS, WKT_H, WKT_L);
    gemm_split<0, true, true><<<dim3(8, 32), 256, 0, stream>>>(
        EO_H, EO_L, WKT_H, WKT_L, nullptr, KPROJ, UNITS, UNITS);

    // decoder (writes hs splits into WCT region, dead)
    decoder_persist<<<256, 512, 0, stream>>>(
        XWFR, de_U, Wq, wv, KPROJ, EOWC, valid_len,
        HWS, CWS, ZWS, QWS, SCWS, HS_H, HS_L, BAR, BAR + 8);

    // Wd^T split (into EOWc region, dead), then logits with [t][b]->[b][t] permute
    transp_split<true><<<dim3(500, 32), 256, 0, stream>>>(Wd, VFR, UNITS, WDT_H, WDT_L);
    gemm_split<1, true, true><<<dim3(125, 32), 256, 0, stream>>>(
        HS_H, HS_L, WDT_H, WDT_L, bd, out, VFR, UNITS);
}